// Round 5
// baseline (88.639 us; speedup 1.0000x reference)
//
#include <hip/hip_runtime.h>
#include <hip/hip_bf16.h>
#include <stdint.h>

#define N_ROWS 16384
#define O_ROWS 1024
#define K_DIM  512

typedef __bf16 bf16x4 __attribute__((ext_vector_type(4)));
typedef __bf16 bf16x8 __attribute__((ext_vector_type(8)));
typedef float  f32x4  __attribute__((ext_vector_type(4)));

__device__ __forceinline__ ushort f2bfu(float f) {
    __bf16 h = (__bf16)f;
    return __builtin_bit_cast(ushort, h);
}

// ---------------------------------------------------------------------------
// Single kernel, no workspace. 128x128 tile, BK=64, 4 waves (2x2), 4x4 frags
// of 16x16x32 bf16 MFMA.
//
// d2 is computed ENTIRELY inside the MFMA accumulator via an extended K-tile:
//   A_ext[r] = [ x_bf16[0..511] | xsq_r, 1, 0.. ]      (32-wide extra tile)
//   B_ext[o] = [ -2*m_bf16[0..511] | 1, msq_o, 0.. ]
//   acc[r][o] = sum_k A_ext*B_ext = -2*x.m + xsq + msq = ||x-m||^2
// Epilogue: out = rsqrt(acc). No scalar xsq/msq broadcast path (the suspect
// in rounds 3/4), no d_ws, no epilogue adds.
// ---------------------------------------------------------------------------
__global__ __launch_bounds__(256) void quadra_kernel(
    const float* __restrict__ x, const float* __restrict__ mean,
    float* __restrict__ out)
{
    __shared__ ushort sA [128 * 64];   // [row][k] bf16, 16 KiB
    __shared__ ushort sB [128 * 64];   // [orow][k] bf16 (-2*mean), 16 KiB
    __shared__ ushort sAe[128 * 32];   // extra tile: [xsq, 1, 0...], 8 KiB
    __shared__ ushort sBe[128 * 32];   // extra tile: [1, msq, 0...], 8 KiB

    const int tid  = threadIdx.x;
    const int lane = tid & 63;
    const int wid  = tid >> 6;
    const int brow = blockIdx.y * 128;
    const int bcol = blockIdx.x * 128;
    const int wr = wid >> 1, wc = wid & 1;   // 2x2 wave grid, 64x64 out each

    f32x4 acc[4][4] = {};

    // staging decomposition: seg = tid>>4 (0..15), q = tid&15.
    // thread handles rows {r8*16 + seg : r8=0..7}, k-quad [q*4, q*4+4).
    const int seg = tid >> 4;
    const int q   = tid & 15;

    const float* gA = x    + (size_t)(brow + seg) * K_DIM + q * 4;
    const float* gB = mean + (size_t)(bcol + seg) * K_DIM + q * 4;

    float asq[8], bsq[8];
    #pragma unroll
    for (int i = 0; i < 8; ++i) { asq[i] = 0.f; bsq[i] = 0.f; }

    for (int kt = 0; kt < K_DIM / 64; ++kt) {
        #pragma unroll
        for (int r8 = 0; r8 < 8; ++r8) {
            f32x4 va = *(const f32x4*)(gA + (size_t)(r8 * 16) * K_DIM + kt * 64);
            f32x4 vb = *(const f32x4*)(gB + (size_t)(r8 * 16) * K_DIM + kt * 64);

            asq[r8] += va[0]*va[0] + va[1]*va[1] + va[2]*va[2] + va[3]*va[3];
            bsq[r8] += vb[0]*vb[0] + vb[1]*vb[1] + vb[2]*vb[2] + vb[3]*vb[3];

            bf16x4 ca, cb;
            ca[0] = (__bf16)va[0]; ca[1] = (__bf16)va[1];
            ca[2] = (__bf16)va[2]; ca[3] = (__bf16)va[3];
            cb[0] = (__bf16)(vb[0] * -2.0f); cb[1] = (__bf16)(vb[1] * -2.0f);
            cb[2] = (__bf16)(vb[2] * -2.0f); cb[3] = (__bf16)(vb[3] * -2.0f);

            *(bf16x4*)(sA + (r8 * 16 + seg) * 64 + q * 4) = ca;
            *(bf16x4*)(sB + (r8 * 16 + seg) * 64 + q * 4) = cb;
        }
        __syncthreads();

        #pragma unroll
        for (int ks = 0; ks < 2; ++ks) {
            bf16x8 a[4], b[4];
            #pragma unroll
            for (int m = 0; m < 4; ++m)
                a[m] = *(const bf16x8*)(sA + (wr*64 + m*16 + (lane & 15)) * 64
                                           + ks*32 + (lane >> 4) * 8);
            #pragma unroll
            for (int n = 0; n < 4; ++n)
                b[n] = *(const bf16x8*)(sB + (wc*64 + n*16 + (lane & 15)) * 64
                                           + ks*32 + (lane >> 4) * 8);
            #pragma unroll
            for (int m = 0; m < 4; ++m)
                #pragma unroll
                for (int n = 0; n < 4; ++n)
                    acc[m][n] = __builtin_amdgcn_mfma_f32_16x16x32_bf16(
                        a[m], b[n], acc[m][n], 0, 0, 0);
        }
        __syncthreads();
    }

    // Reduce row norms over each 16-lane segment group and stage the
    // 32-wide extended K-tile. Every thread writes (q!=0 writes zeros):
    //   sAe[row] = [ xsq, 1.0, 0 x30 ]   sBe[row] = [ 1.0, msq, 0 x30 ]
    #pragma unroll
    for (int r8 = 0; r8 < 8; ++r8) {
        float sa = asq[r8], sb = bsq[r8];
        #pragma unroll
        for (int msk = 1; msk < 16; msk <<= 1) {
            sa += __shfl_xor(sa, msk);
            sb += __shfl_xor(sb, msk);
        }
        const int row = r8 * 16 + seg;
        uint32_t aw = 0, bw = 0;
        if (q == 0) {
            aw = (uint32_t)f2bfu(sa) | (0x3F80u << 16);   // [xsq, 1.0]
            bw = 0x3F80u | ((uint32_t)f2bfu(sb) << 16);   // [1.0, msq]
        }
        *(uint32_t*)(sAe + row * 32 + q * 2) = aw;
        *(uint32_t*)(sBe + row * 32 + q * 2) = bw;
    }
    __syncthreads();

    // extra-tile MFMA: adds xsq[r] + msq[o] into every accumulator element
    {
        bf16x8 a[4], b[4];
        #pragma unroll
        for (int m = 0; m < 4; ++m)
            a[m] = *(const bf16x8*)(sAe + (wr*64 + m*16 + (lane & 15)) * 32
                                        + (lane >> 4) * 8);
        #pragma unroll
        for (int n = 0; n < 4; ++n)
            b[n] = *(const bf16x8*)(sBe + (wc*64 + n*16 + (lane & 15)) * 32
                                        + (lane >> 4) * 8);
        #pragma unroll
        for (int m = 0; m < 4; ++m)
            #pragma unroll
            for (int n = 0; n < 4; ++n)
                acc[m][n] = __builtin_amdgcn_mfma_f32_16x16x32_bf16(
                    a[m], b[n], acc[m][n], 0, 0, 0);
    }

    // epilogue: C/D layout col = lane&15, row = (lane>>4)*4 + j
    const int cl = lane & 15, rg = lane >> 4;
    #pragma unroll
    for (int m = 0; m < 4; ++m) {
        #pragma unroll
        for (int j = 0; j < 4; ++j) {
            const int grow = brow + wr*64 + m*16 + rg*4 + j;
            float* orow = out + (size_t)grow * O_ROWS + bcol + wc*64 + cl;
            #pragma unroll
            for (int n = 0; n < 4; ++n)
                orow[n * 16] = rsqrtf(acc[m][n][j]);
        }
    }
}

extern "C" void kernel_launch(void* const* d_in, const int* in_sizes, int n_in,
                              void* d_out, int out_size, void* d_ws, size_t ws_size,
                              hipStream_t stream) {
    const float* x    = (const float*)d_in[0];
    const float* mean = (const float*)d_in[1];
    float* out = (float*)d_out;

    dim3 grid(O_ROWS / 128, N_ROWS / 128);
    quadra_kernel<<<grid, 256, 0, stream>>>(x, mean, out);
}